// Round 1
// baseline (4644.793 us; speedup 1.0000x reference)
//
#include <hip/hip_runtime.h>
#include <cstdint>
#include <cstddef>

typedef __bf16 bf16;
typedef __bf16 bf16x8 __attribute__((ext_vector_type(8)));
typedef __bf16 bf16x4 __attribute__((ext_vector_type(4)));
typedef float  f32x4  __attribute__((ext_vector_type(4)));

#define NV 32000
#define NE 256
#define NH 512
#define NB 32
#define NS 128
#define NT 64
#define NTD 63           // decoder steps = T-1
#define G4H 2048         // 4*H

__device__ __forceinline__ float sigf(float x) {
    return 1.0f / (1.0f + __expf(-x));
}
__device__ __forceinline__ float tanhf_(float x) {
    // 1 - 2/(e^{2x}+1); saturates correctly for large |x|
    return 1.0f - 2.0f / (__expf(2.0f * x) + 1.0f);
}

// ---------------------------------------------------------------------------
// Prep kernels
// ---------------------------------------------------------------------------
__global__ void k_cast_fcW(const float* __restrict__ src, bf16* __restrict__ dst, int n4) {
    int i = blockIdx.x * 256 + threadIdx.x;
    if (i < n4) {
        float4 v = *(const float4*)(src + 4 * (size_t)i);
        bf16x4 o;
        o[0] = (bf16)v.x; o[1] = (bf16)v.y; o[2] = (bf16)v.z; o[3] = (bf16)v.w;
        *(bf16x4*)(dst + 4 * (size_t)i) = o;
    }
}

__global__ void k_cast_small(const float* __restrict__ encWih, const float* __restrict__ decWih,
                             const float* __restrict__ attnW,
                             const float* __restrict__ ebih, const float* __restrict__ ebhh,
                             const float* __restrict__ dbih, const float* __restrict__ dbhh,
                             bf16* __restrict__ encWihB, bf16* __restrict__ decWihXB,
                             bf16* __restrict__ attnWeB,
                             float* __restrict__ bsumE, float* __restrict__ bsumD,
                             float* __restrict__ cbuf) {
    int i = blockIdx.x * 256 + threadIdx.x;
    const int n1 = G4H * NE;       // encWih cast (layout identical)
    const int n2 = G4H * NE;       // decWih x-part pack
    const int n3 = NH * NH;        // attn_W e-part pack
    if (i < n1) { encWihB[i] = (bf16)encWih[i]; return; }
    i -= n1;
    if (i < n2) { int r = i >> 8, c = i & 255; decWihXB[i] = (bf16)decWih[(size_t)r * 768 + c]; return; }
    i -= n2;
    if (i < n3) { int r = i >> 9, c = i & 511; attnWeB[i] = (bf16)attnW[(size_t)r * 1024 + 512 + c]; return; }
    i -= n3;
    if (i < G4H) { bsumE[i] = ebih[i] + ebhh[i]; return; }
    i -= G4H;
    if (i < G4H) { bsumD[i] = dbih[i] + dbhh[i]; return; }
    i -= G4H;
    if (i < NB * NH) { cbuf[i] = 0.0f; return; }
}

__global__ void k_embed(const int* __restrict__ src, const int* __restrict__ tgt,
                        const float* __restrict__ embed,
                        bf16* __restrict__ srcE, bf16* __restrict__ decE) {
    int i = blockIdx.x * 256 + threadIdx.x;
    const int nS = NB * NS * NE;
    if (i < nS) {
        int r = i >> 8, e = i & 255;
        srcE[i] = (bf16)embed[(size_t)src[r] * NE + e];
        return;
    }
    i -= nS;
    const int nD = NB * NTD * NE;
    if (i < nD) {
        int r = i >> 8, e = i & 255;
        int bb = r / NTD, tt = r % NTD;
        decE[i] = (bf16)embed[(size_t)tgt[bb * NT + tt] * NE + e];
    }
}

// ---------------------------------------------------------------------------
// bf16 MFMA GEMM: C[M,N] = A[M,K] @ B[N,K]^T + bias[N]   (fp32 out)
// 128x128 tile, BK=64, 256 threads (4 waves, each 64x64)
// ---------------------------------------------------------------------------
__global__ __launch_bounds__(256) void k_gemm(const bf16* __restrict__ A,
                                              const bf16* __restrict__ Bw,
                                              const float* __restrict__ bias,
                                              float* __restrict__ C,
                                              int M, int N, int K) {
    const int bn = blockIdx.x * 128;
    const int bm = blockIdx.y * 128;
    const int tid = threadIdx.x;
    __shared__ bf16 As[128 * 72];   // pad 64->72 bf16 to break conflicts
    __shared__ bf16 Bs[128 * 72];
    const int wave = tid >> 6, lane = tid & 63;
    const int wm = (wave >> 1) * 64, wn = (wave & 1) * 64;
    const int r16 = lane & 15, quad = lane >> 4;

    f32x4 acc[4][4];
#pragma unroll
    for (int i = 0; i < 4; i++)
#pragma unroll
        for (int j = 0; j < 4; j++)
#pragma unroll
            for (int e = 0; e < 4; e++) acc[i][j][e] = 0.0f;

    for (int kb = 0; kb < K; kb += 64) {
#pragma unroll
        for (int i = 0; i < 4; i++) {
            int ci = tid + i * 256;          // 1024 chunks of 8 bf16
            int row = ci >> 3, kc = (ci & 7) * 8;
            bf16x8 va;
#pragma unroll
            for (int z = 0; z < 8; z++) va[z] = (bf16)0.0f;
            int gr = bm + row;
            if (gr < M) va = *(const bf16x8*)(A + (size_t)gr * K + kb + kc);
            *(bf16x8*)(As + row * 72 + kc) = va;
            bf16x8 vb = *(const bf16x8*)(Bw + (size_t)(bn + row) * K + kb + kc);
            *(bf16x8*)(Bs + row * 72 + kc) = vb;
        }
        __syncthreads();
#pragma unroll
        for (int ks = 0; ks < 2; ks++) {
            bf16x8 af[4], bfr[4];
#pragma unroll
            for (int mi = 0; mi < 4; mi++)
                af[mi] = *(const bf16x8*)(As + (wm + mi * 16 + r16) * 72 + ks * 32 + quad * 8);
#pragma unroll
            for (int ni = 0; ni < 4; ni++)
                bfr[ni] = *(const bf16x8*)(Bs + (wn + ni * 16 + r16) * 72 + ks * 32 + quad * 8);
#pragma unroll
            for (int mi = 0; mi < 4; mi++)
#pragma unroll
                for (int ni = 0; ni < 4; ni++)
                    acc[mi][ni] = __builtin_amdgcn_mfma_f32_16x16x32_bf16(af[mi], bfr[ni], acc[mi][ni], 0, 0, 0);
        }
        __syncthreads();
    }
#pragma unroll
    for (int mi = 0; mi < 4; mi++) {
#pragma unroll
        for (int e = 0; e < 4; e++) {
            int row = bm + wm + mi * 16 + quad * 4 + e;
            if (row < M) {
#pragma unroll
                for (int ni = 0; ni < 4; ni++) {
                    int col = bn + wn + ni * 16 + r16;
                    C[(size_t)row * N + col] = acc[mi][ni][e] + bias[col];
                }
            }
        }
    }
}

// ---------------------------------------------------------------------------
// Encoder step: gates = X_enc[:,t,:] + h_{t-1} @ Whh^T ; LSTM update
// grid 128 blocks x 256 thr; block owns hidden dims d0..d0+3 (x4 gates = 16 rows)
// ---------------------------------------------------------------------------
__global__ __launch_bounds__(256) void k_enc_step(const float* __restrict__ Xenc,
                                                  const float* __restrict__ Whh,
                                                  float* __restrict__ enc_out,
                                                  bf16* __restrict__ enc_out_b,
                                                  float* __restrict__ cbuf, int t) {
    const int blk = blockIdx.x;
    const int d0 = blk * 4;
    const int tid = threadIdx.x;
    __shared__ float wl[16 * 516];
    __shared__ float gl[16 * 33];

#pragma unroll
    for (int i = 0; i < 8; i++) {            // 16 rows x 512 = 2048 float4
        int ci = tid + i * 256;
        int ri = ci >> 7, kc = (ci & 127) * 4;
        int j = ((ri >> 2) * NH) + d0 + (ri & 3);
        *(float4*)(wl + ri * 516 + kc) = *(const float4*)(Whh + (size_t)j * NH + kc);
    }
    __syncthreads();

    const int b = tid >> 3, rl = tid & 7;
    float a0 = 0.0f, a1 = 0.0f;
    if (t > 0) {
        const float* hb = enc_out + ((size_t)(b * NS + t - 1)) * NH;  // h_{t-1}[b]
        const float* w0 = wl + rl * 516;
        const float* w1 = wl + (rl + 8) * 516;
        for (int kc = 0; kc < NH; kc += 4) {
            float4 h4 = *(const float4*)(hb + kc);
            float4 x0 = *(const float4*)(w0 + kc);
            float4 x1 = *(const float4*)(w1 + kc);
            a0 += h4.x * x0.x + h4.y * x0.y + h4.z * x0.z + h4.w * x0.w;
            a1 += h4.x * x1.x + h4.y * x1.y + h4.z * x1.z + h4.w * x1.w;
        }
    }
    {
        int j0 = ((rl >> 2) * NH) + d0 + (rl & 3);
        int j1 = (((rl + 8) >> 2) * NH) + d0 + ((rl + 8) & 3);
        const float* xr = Xenc + ((size_t)(b * NS + t)) * G4H;
        a0 += xr[j0];
        a1 += xr[j1];
        gl[rl * 33 + b] = a0;
        gl[(rl + 8) * 33 + b] = a1;
    }
    __syncthreads();
    if (tid < 128) {
        int bb = tid & 31, dl = tid >> 5;
        float gi = gl[(0 * 4 + dl) * 33 + bb];
        float gf = gl[(1 * 4 + dl) * 33 + bb];
        float gg = gl[(2 * 4 + dl) * 33 + bb];
        float go = gl[(3 * 4 + dl) * 33 + bb];
        int d = d0 + dl;
        float c_old = cbuf[bb * NH + d];
        float cn = sigf(gf) * c_old + sigf(gi) * tanhf_(gg);
        float hn = sigf(go) * tanhf_(cn);
        cbuf[bb * NH + d] = cn;
        size_t oi = ((size_t)(bb * NS + t)) * NH + d;
        enc_out[oi] = hn;
        enc_out_b[oi] = (bf16)hn;
    }
}

// ---------------------------------------------------------------------------
// Decoder mm1: Gp = h @ dec_Whh^T (2048 rows) and hWh = h @ W_h^T (512 rows)
// grid 160 blocks x 256
// ---------------------------------------------------------------------------
__global__ __launch_bounds__(256) void k_dec_mm1(const float* __restrict__ decWhh,
                                                 const float* __restrict__ attnW,
                                                 const float* __restrict__ enc_out,
                                                 const float* __restrict__ hbuf,
                                                 float* __restrict__ Gp,
                                                 float* __restrict__ hWh, int t) {
    const int blk = blockIdx.x;
    const int tid = threadIdx.x;
    __shared__ float wl[16 * 516];
    const bool gatePart = blk < 128;

#pragma unroll
    for (int i = 0; i < 8; i++) {
        int ci = tid + i * 256;
        int ri = ci >> 7, kc = (ci & 127) * 4;
        const float* srcp;
        if (gatePart) srcp = decWhh + (size_t)(blk * 16 + ri) * NH + kc;
        else          srcp = attnW + (size_t)((blk - 128) * 16 + ri) * 1024 + kc;
        *(float4*)(wl + ri * 516 + kc) = *(const float4*)srcp;
    }
    __syncthreads();

    const int b = tid >> 3, rl = tid & 7;
    const float* hb;
    if (t == 0) hb = enc_out + ((size_t)(b * NS + NS - 1)) * NH;   // encoder final h
    else        hb = hbuf + (size_t)b * NH;
    const float* w0 = wl + rl * 516;
    const float* w1 = wl + (rl + 8) * 516;
    float a0 = 0.0f, a1 = 0.0f;
    for (int kc = 0; kc < NH; kc += 4) {
        float4 h4 = *(const float4*)(hb + kc);
        float4 x0 = *(const float4*)(w0 + kc);
        float4 x1 = *(const float4*)(w1 + kc);
        a0 += h4.x * x0.x + h4.y * x0.y + h4.z * x0.z + h4.w * x0.w;
        a1 += h4.x * x1.x + h4.y * x1.y + h4.z * x1.z + h4.w * x1.w;
    }
    if (gatePart) {
        int j0 = blk * 16 + rl;
        Gp[b * G4H + j0] = a0;
        Gp[b * G4H + j0 + 8] = a1;
    } else {
        int r0 = (blk - 128) * 16 + rl;
        hWh[b * NH + r0] = a0;
        hWh[b * NH + r0 + 8] = a1;
    }
}

// ---------------------------------------------------------------------------
// Decoder attention: scores -> softmax -> context, per batch element
// grid 32 blocks x 256
// ---------------------------------------------------------------------------
__global__ __launch_bounds__(256) void k_dec_attn(const float* __restrict__ hWh,
                                                  const float* __restrict__ attn_v,
                                                  const float* __restrict__ enc_proj,
                                                  const float* __restrict__ enc_out,
                                                  float* __restrict__ ctx) {
    const int b = blockIdx.x;
    const int tid = threadIdx.x;
    __shared__ float hw[512], vv[512], ps[256], sc[128], red[64];
    hw[tid] = hWh[b * NH + tid];
    hw[tid + 256] = hWh[b * NH + tid + 256];
    vv[tid] = attn_v[tid];
    vv[tid + 256] = attn_v[tid + 256];
    __syncthreads();

    const int s = tid >> 1, hf = tid & 1;
    const float* ep = enc_proj + ((size_t)(b * NS + s)) * NH + hf * 256;
    const float* hwp = hw + hf * 256;
    const float* vvp = vv + hf * 256;
    float p = 0.0f;
    for (int k = 0; k < 256; k += 4) {
        float4 e = *(const float4*)(ep + k);
        p += tanhf_(hwp[k + 0] + e.x) * vvp[k + 0];
        p += tanhf_(hwp[k + 1] + e.y) * vvp[k + 1];
        p += tanhf_(hwp[k + 2] + e.z) * vvp[k + 2];
        p += tanhf_(hwp[k + 3] + e.w) * vvp[k + 3];
    }
    ps[tid] = p;
    __syncthreads();
    if (tid < 128) sc[tid] = ps[2 * tid] + ps[2 * tid + 1];
    __syncthreads();
    // max reduce
    if (tid < 64) red[tid] = fmaxf(sc[tid], sc[tid + 64]);
    __syncthreads();
    if (tid < 32) red[tid] = fmaxf(red[tid], red[tid + 32]);
    __syncthreads();
    if (tid < 16) red[tid] = fmaxf(red[tid], red[tid + 16]);
    __syncthreads();
    if (tid < 8) red[tid] = fmaxf(red[tid], red[tid + 8]);
    __syncthreads();
    if (tid < 4) red[tid] = fmaxf(red[tid], red[tid + 4]);
    __syncthreads();
    if (tid < 2) red[tid] = fmaxf(red[tid], red[tid + 2]);
    __syncthreads();
    if (tid == 0) red[0] = fmaxf(red[0], red[1]);
    __syncthreads();
    float mx = red[0];
    __syncthreads();
    if (tid < 128) sc[tid] = __expf(sc[tid] - mx);
    __syncthreads();
    // sum reduce
    if (tid < 64) red[tid] = sc[tid] + sc[tid + 64];
    __syncthreads();
    if (tid < 32) red[tid] = red[tid] + red[tid + 32];
    __syncthreads();
    if (tid < 16) red[tid] = red[tid] + red[tid + 16];
    __syncthreads();
    if (tid < 8) red[tid] = red[tid] + red[tid + 8];
    __syncthreads();
    if (tid < 4) red[tid] = red[tid] + red[tid + 4];
    __syncthreads();
    if (tid < 2) red[tid] = red[tid] + red[tid + 2];
    __syncthreads();
    if (tid == 0) red[0] = red[0] + red[1];
    __syncthreads();
    float inv = 1.0f / red[0];
    __syncthreads();
    if (tid < 128) sc[tid] *= inv;
    __syncthreads();
    // context
#pragma unroll
    for (int half = 0; half < 2; half++) {
        int k = tid + half * 256;
        float a = 0.0f;
        const float* eo = enc_out + ((size_t)(b * NS)) * NH + k;
        for (int s2 = 0; s2 < NS; s2++) a += sc[s2] * eo[(size_t)s2 * NH];
        ctx[b * NH + k] = a;
    }
}

// ---------------------------------------------------------------------------
// Decoder final: gates = Gp + X_dec + ctx @ WihC^T ; LSTM update; write hs_bf16
// grid 128 x 256
// ---------------------------------------------------------------------------
__global__ __launch_bounds__(256) void k_dec_final(const float* __restrict__ Xdec,
                                                   const float* __restrict__ decWih,
                                                   const float* __restrict__ Gp,
                                                   const float* __restrict__ ctx,
                                                   float* __restrict__ cbuf,
                                                   float* __restrict__ hbuf,
                                                   bf16* __restrict__ hs_b, int t) {
    const int blk = blockIdx.x;
    const int d0 = blk * 4;
    const int tid = threadIdx.x;
    __shared__ float wl[16 * 516];
    __shared__ float gl[16 * 33];

#pragma unroll
    for (int i = 0; i < 8; i++) {
        int ci = tid + i * 256;
        int ri = ci >> 7, kc = (ci & 127) * 4;
        int j = ((ri >> 2) * NH) + d0 + (ri & 3);
        *(float4*)(wl + ri * 516 + kc) = *(const float4*)(decWih + (size_t)j * 768 + 256 + kc);
    }
    __syncthreads();

    const int b = tid >> 3, rl = tid & 7;
    const float* cb = ctx + (size_t)b * NH;
    const float* w0 = wl + rl * 516;
    const float* w1 = wl + (rl + 8) * 516;
    float a0 = 0.0f, a1 = 0.0f;
    for (int kc = 0; kc < NH; kc += 4) {
        float4 h4 = *(const float4*)(cb + kc);
        float4 x0 = *(const float4*)(w0 + kc);
        float4 x1 = *(const float4*)(w1 + kc);
        a0 += h4.x * x0.x + h4.y * x0.y + h4.z * x0.z + h4.w * x0.w;
        a1 += h4.x * x1.x + h4.y * x1.y + h4.z * x1.z + h4.w * x1.w;
    }
    {
        int j0 = ((rl >> 2) * NH) + d0 + (rl & 3);
        int j1 = (((rl + 8) >> 2) * NH) + d0 + ((rl + 8) & 3);
        const float* xr = Xdec + ((size_t)(b * NTD + t)) * G4H;
        a0 += xr[j0] + Gp[b * G4H + j0];
        a1 += xr[j1] + Gp[b * G4H + j1];
        gl[rl * 33 + b] = a0;
        gl[(rl + 8) * 33 + b] = a1;
    }
    __syncthreads();
    if (tid < 128) {
        int bb = tid & 31, dl = tid >> 5;
        float gi = gl[(0 * 4 + dl) * 33 + bb];
        float gf = gl[(1 * 4 + dl) * 33 + bb];
        float gg = gl[(2 * 4 + dl) * 33 + bb];
        float go = gl[(3 * 4 + dl) * 33 + bb];
        int d = d0 + dl;
        float c_old = cbuf[bb * NH + d];
        float cn = sigf(gf) * c_old + sigf(gi) * tanhf_(gg);
        float hn = sigf(go) * tanhf_(cn);
        cbuf[bb * NH + d] = cn;
        hbuf[bb * NH + d] = hn;
        hs_b[((size_t)(bb * NTD + t)) * NH + d] = (bf16)hn;
    }
}

// ---------------------------------------------------------------------------
extern "C" void kernel_launch(void* const* d_in, const int* in_sizes, int n_in,
                              void* d_out, int out_size, void* d_ws, size_t ws_size,
                              hipStream_t stream) {
    const int* src = (const int*)d_in[0];
    const int* tgt = (const int*)d_in[1];
    const float* embed = (const float*)d_in[2];
    const float* encWih = (const float*)d_in[3];
    const float* encWhh = (const float*)d_in[4];
    const float* encbih = (const float*)d_in[5];
    const float* encbhh = (const float*)d_in[6];
    const float* decWih = (const float*)d_in[7];
    const float* decWhh = (const float*)d_in[8];
    const float* decbih = (const float*)d_in[9];
    const float* decbhh = (const float*)d_in[10];
    const float* attnW = (const float*)d_in[11];
    const float* attnb = (const float*)d_in[12];
    const float* attnv = (const float*)d_in[13];
    const float* fcW = (const float*)d_in[14];
    const float* fcb = (const float*)d_in[15];
    float* out = (float*)d_out;

    char* w = (char*)d_ws;
    auto alloc = [&](size_t bytes) -> char* {
        char* p = w;
        w += (bytes + 255) & ~(size_t)255;
        return p;
    };
    bf16* fcWB     = (bf16*)alloc((size_t)NV * NH * 2);
    bf16* encWihB  = (bf16*)alloc((size_t)G4H * NE * 2);
    bf16* decWihXB = (bf16*)alloc((size_t)G4H * NE * 2);
    bf16* attnWeB  = (bf16*)alloc((size_t)NH * NH * 2);
    bf16* srcE     = (bf16*)alloc((size_t)NB * NS * NE * 2);
    bf16* decE     = (bf16*)alloc((size_t)NB * NTD * NE * 2);
    float* bsumE   = (float*)alloc((size_t)G4H * 4);
    float* bsumD   = (float*)alloc((size_t)G4H * 4);
    float* Xenc    = (float*)alloc((size_t)NB * NS * G4H * 4);
    float* Xdec    = (float*)alloc((size_t)NB * NTD * G4H * 4);
    float* enc_out = (float*)alloc((size_t)NB * NS * NH * 4);
    bf16* enc_outB = (bf16*)alloc((size_t)NB * NS * NH * 2);
    float* encproj = (float*)alloc((size_t)NB * NS * NH * 4);
    float* cbuf    = (float*)alloc((size_t)NB * NH * 4);
    float* hbuf    = (float*)alloc((size_t)NB * NH * 4);
    float* Gp      = (float*)alloc((size_t)NB * G4H * 4);
    float* hWh     = (float*)alloc((size_t)NB * NH * 4);
    float* ctx     = (float*)alloc((size_t)NB * NH * 4);
    bf16* hsB      = (bf16*)alloc((size_t)NB * NTD * NH * 2);
    (void)ws_size; (void)in_sizes; (void)n_in; (void)out_size;

    // --- prep ---
    {
        int n4 = NV * NH / 4;
        k_cast_fcW<<<(n4 + 255) / 256, 256, 0, stream>>>(fcW, fcWB, n4);
        int tot = G4H * NE + G4H * NE + NH * NH + G4H + G4H + NB * NH;
        k_cast_small<<<(tot + 255) / 256, 256, 0, stream>>>(encWih, decWih, attnW,
                                                            encbih, encbhh, decbih, decbhh,
                                                            encWihB, decWihXB, attnWeB,
                                                            bsumE, bsumD, cbuf);
        int te = NB * NS * NE + NB * NTD * NE;
        k_embed<<<(te + 255) / 256, 256, 0, stream>>>(src, tgt, embed, srcE, decE);
    }
    // --- input projections (MFMA GEMMs) ---
    k_gemm<<<dim3(G4H / 128, (NB * NS) / 128), 256, 0, stream>>>(srcE, encWihB, bsumE, Xenc,
                                                                 NB * NS, G4H, NE);
    k_gemm<<<dim3(G4H / 128, (NB * NTD + 127) / 128), 256, 0, stream>>>(decE, decWihXB, bsumD, Xdec,
                                                                        NB * NTD, G4H, NE);
    // --- encoder recurrence ---
    for (int t = 0; t < NS; t++)
        k_enc_step<<<128, 256, 0, stream>>>(Xenc, encWhh, enc_out, enc_outB, cbuf, t);
    // --- enc_proj ---
    k_gemm<<<dim3(NH / 128, (NB * NS) / 128), 256, 0, stream>>>(enc_outB, attnWeB, attnb, encproj,
                                                                NB * NS, NH, NH);
    // --- decoder ---
    for (int t = 0; t < NTD; t++) {
        k_dec_mm1<<<160, 256, 0, stream>>>(decWhh, attnW, enc_out, hbuf, Gp, hWh, t);
        k_dec_attn<<<32, 256, 0, stream>>>(hWh, attnv, encproj, enc_out, ctx);
        k_dec_final<<<128, 256, 0, stream>>>(Xdec, decWih, Gp, ctx, cbuf, hbuf, hsB, t);
    }
    // --- logits ---
    k_gemm<<<dim3(NV / 128, (NB * NTD + 127) / 128), 256, 0, stream>>>(hsB, fcWB, fcb, out,
                                                                       NB * NTD, NV, NH);
}